// Round 1
// baseline (361.334 us; speedup 1.0000x reference)
//
#include <hip/hip_runtime.h>

#define L_   8192
#define H_   128
#define T_   4095      // (8192-3)/2 + 1
#define CH_  16        // scan chunk length
#define NC_  256       // number of chunks (255 full + 1 of 15)

typedef __bf16 bf16x8 __attribute__((ext_vector_type(8)));
typedef unsigned short ushort8 __attribute__((ext_vector_type(8)));
typedef float f32x4 __attribute__((ext_vector_type(4)));

__device__ __forceinline__ unsigned short f2bf(float f) {
    // round-to-nearest-even fp32 -> bf16 bits
    unsigned int u = __builtin_bit_cast(unsigned int, f);
    u += 0x7fffu + ((u >> 16) & 1u);
    return (unsigned short)(u >> 16);
}

// ---------------- os[t,h] = sum_w D[w] * X[2t+w, h] ----------------
__global__ __launch_bounds__(256) void os_kernel(const float* __restrict__ X,
                                                 const float* __restrict__ Dv,
                                                 float* __restrict__ os) {
    int i = blockIdx.x * 256 + threadIdx.x;       // i = t*128 + h
    if (i >= T_ * H_) return;
    int t = i >> 7, h = i & 127;
    const float* xr = X + (size_t)(2 * t) * H_ + h;
    os[i] = Dv[0] * xr[0] + Dv[1] * xr[H_] + Dv[2] * xr[2 * H_];
}

// ---------------- pass 1: per-chunk local scan end values ----------------
// ebuf[c][entry] = sum_{s in chunk c} lam^(t_end-s) * u[s]   (zero init)
__global__ __launch_bounds__(256) void pass1_kernel(const float* __restrict__ X,
                                                    const float* __restrict__ Lam,
                                                    const float* __restrict__ wq,
                                                    float* __restrict__ ebuf) {
    const int c     = blockIdx.x;
    const int entry = blockIdx.y * 256 + threadIdx.x;   // a*128 + d
    const int a = entry >> 7, d = entry & 127;
    const float lam = Lam[entry];
    const float w00 = wq[0], w01 = wq[1], w02 = wq[2];
    const float w10 = wq[3], w11 = wq[4], w12 = wq[5];
    const float w20 = wq[6], w21 = wq[7], w22 = wq[8];

    const int t0 = c * CH_;
    const int t1 = min(t0 + CH_, T_);
    const float* xr0 = X + (size_t)(2 * t0) * H_;
    float xa0 = xr0[a], xa1 = xr0[H_ + a];
    float xd0 = xr0[d], xd1 = xr0[H_ + d];
    float z = 0.f;
    for (int t = t0; t < t1; ++t) {
        const float* x2 = X + (size_t)(2 * t) * H_ + 2 * H_;   // row 2t+2
        float xa2 = x2[a], xd2 = x2[d];
        float y0 = w00 * xd0 + w01 * xd1 + w02 * xd2;
        float y1 = w10 * xd0 + w11 * xd1 + w12 * xd2;
        float y2 = w20 * xd0 + w21 * xd1 + w22 * xd2;
        float u  = xa0 * y0 + xa1 * y1 + xa2 * y2;
        z = fmaf(lam, z, u);
        // roll: next t uses rows 2t+2, 2t+3 as its first two (2t+3 <= 8191, in-bounds)
        xa0 = xa2; xd0 = xd2;
        xa1 = x2[H_ + a]; xd1 = x2[H_ + d];
    }
    ebuf[(size_t)c * (H_ * H_) + entry] = z;
}

// ---------------- pass 2: cross-chunk scan, in place e -> carry_in ----------------
__global__ __launch_bounds__(256) void pass2_kernel(const float* __restrict__ Lam,
                                                    float* __restrict__ ebuf) {
    const int entry = blockIdx.x * 256 + threadIdx.x;
    const float lam = Lam[entry];
    float p = lam * lam; p = p * p; p = p * p; p = p * p;   // lam^16
    float z = 0.f;
    for (int cb = 0; cb < NC_; cb += 8) {
        float tmp[8];
        #pragma unroll
        for (int i = 0; i < 8; ++i)
            tmp[i] = ebuf[(size_t)(cb + i) * (H_ * H_) + entry];
        #pragma unroll
        for (int i = 0; i < 8; ++i) {
            ebuf[(size_t)(cb + i) * (H_ * H_) + entry] = z;   // carry_in[chunk]
            z = fmaf(p, z, tmp[i]);
        }
    }
}

// ---------------- pass 3: replay scan from carry + per-t MFMA GEMM ----------------
// block: (chunk c, a-tile of 32).  out[t, h, a0+ja] = sum_d C[h,d] * zs[t, a0+ja, d]
__global__ __launch_bounds__(256) void pass3_kernel(const float* __restrict__ X,
                                                    const float* __restrict__ Lam,
                                                    const float* __restrict__ Cm,
                                                    const float* __restrict__ wq,
                                                    const float* __restrict__ carry,
                                                    float* __restrict__ out) {
    __shared__ unsigned short z_s[32][136];   // bf16 zs tile [a_local][d], pad 136 (16B-aligned rows)
    __shared__ float y_s[3][128];
    __shared__ float xa_s[3][32];

    const int tid  = threadIdx.x;
    const int c    = blockIdx.x;
    const int a0   = blockIdx.y * 32;
    const int lane = tid & 63;
    const int wave = tid >> 6;
    const int m    = lane & 15;
    const int q    = lane >> 4;

    // A-fragments: bf16 C rows, resident in registers for the whole block.
    // wave handles M-tiles {2*wave, 2*wave+1}; A[m][k] = C[Mtile*16+m][kt*32+q*8+j]
    ushort8 afrag[2][4];
    #pragma unroll
    for (int mi = 0; mi < 2; ++mi) {
        const int h = (wave * 2 + mi) * 16 + m;
        #pragma unroll
        for (int kt = 0; kt < 4; ++kt) {
            const float* src = Cm + h * 128 + kt * 32 + q * 8;
            ushort8 v;
            #pragma unroll
            for (int j = 0; j < 8; ++j) v[j] = f2bf(src[j]);
            afrag[mi][kt] = v;
        }
    }

    // scan ownership: a_l = tid&31 (one a-row), d = dg*16 + j (16 entries)
    const int a_l = tid & 31;
    const int dg  = tid >> 5;
    float z[16], lam[16];
    {
        const float* lp = Lam   + (size_t)(a0 + a_l) * 128 + dg * 16;
        const float* cp = carry + (size_t)c * (H_ * H_) + (size_t)(a0 + a_l) * 128 + dg * 16;
        #pragma unroll
        for (int j = 0; j < 16; ++j) { lam[j] = lp[j]; z[j] = cp[j]; }
    }
    const float w00 = wq[0], w01 = wq[1], w02 = wq[2];
    const float w10 = wq[3], w11 = wq[4], w12 = wq[5];
    const float w20 = wq[6], w21 = wq[7], w22 = wq[8];

    const int t0 = c * CH_;
    const int t1 = min(t0 + CH_, T_);

    for (int t = t0; t < t1; ++t) {
        __syncthreads();   // z_s free (prev MFMA done), y_s free (prev scan done)
        const float* xr = X + (size_t)(2 * t) * H_;
        if (tid < 128) {
            float xd0 = xr[tid], xd1 = xr[H_ + tid], xd2 = xr[2 * H_ + tid];
            y_s[0][tid] = w00 * xd0 + w01 * xd1 + w02 * xd2;
            y_s[1][tid] = w10 * xd0 + w11 * xd1 + w12 * xd2;
            y_s[2][tid] = w20 * xd0 + w21 * xd1 + w22 * xd2;
        } else if (tid < 224) {
            int li = tid - 128;                       // w = li>>5, a_local = li&31
            xa_s[li >> 5][li & 31] = xr[(li >> 5) * H_ + a0 + (li & 31)];
        }
        __syncthreads();

        {   // fp32 recurrence in registers; publish bf16 to z_s
            const float xa0 = xa_s[0][a_l], xa1 = xa_s[1][a_l], xa2 = xa_s[2][a_l];
            #pragma unroll
            for (int j = 0; j < 16; ++j) {
                const int d = dg * 16 + j;
                float u = xa0 * y_s[0][d] + xa1 * y_s[1][d] + xa2 * y_s[2][d];
                z[j] = fmaf(lam[j], z[j], u);
            }
            ushort8 zb0, zb1;
            #pragma unroll
            for (int j = 0; j < 8; ++j) { zb0[j] = f2bf(z[j]); zb1[j] = f2bf(z[j + 8]); }
            *(ushort8*)&z_s[a_l][dg * 16]     = zb0;
            *(ushort8*)&z_s[a_l][dg * 16 + 8] = zb1;
        }
        __syncthreads();

        // MFMA: D[h, a] tiles; B[k=d][n=a]: lane reads z_s[nt*16+m][kt*32+q*8 .. +7]
        f32x4 acc[2][2] = {};
        #pragma unroll
        for (int kt = 0; kt < 4; ++kt) {
            bf16x8 b0 = __builtin_bit_cast(bf16x8, *(const ushort8*)&z_s[m][kt * 32 + q * 8]);
            bf16x8 b1 = __builtin_bit_cast(bf16x8, *(const ushort8*)&z_s[16 + m][kt * 32 + q * 8]);
            #pragma unroll
            for (int mi = 0; mi < 2; ++mi) {
                bf16x8 a = __builtin_bit_cast(bf16x8, afrag[mi][kt]);
                acc[mi][0] = __builtin_amdgcn_mfma_f32_16x16x32_bf16(a, b0, acc[mi][0], 0, 0, 0);
                acc[mi][1] = __builtin_amdgcn_mfma_f32_16x16x32_bf16(a, b1, acc[mi][1], 0, 0, 0);
            }
        }
        // D layout: row = q*4 + r (h within tile), col = m (a within tile)
        float* ob = out + (size_t)t * (H_ * H_) + a0;
        #pragma unroll
        for (int mi = 0; mi < 2; ++mi) {
            const int hb = (wave * 2 + mi) * 16 + q * 4;
            #pragma unroll
            for (int r = 0; r < 4; ++r) {
                ob[(size_t)(hb + r) * H_ + m]      = acc[mi][0][r];
                ob[(size_t)(hb + r) * H_ + 16 + m] = acc[mi][1][r];
            }
        }
    }
}

extern "C" void kernel_launch(void* const* d_in, const int* in_sizes, int n_in,
                              void* d_out, int out_size, void* d_ws, size_t ws_size,
                              hipStream_t stream) {
    const float* X   = (const float*)d_in[0];   // (L, H)
    const float* Lam = (const float*)d_in[1];   // (H, H)
    const float* Cm  = (const float*)d_in[2];   // (H, H)
    const float* wq  = (const float*)d_in[3];   // (3, 3)
    const float* Dv  = (const float*)d_in[4];   // (3,)
    float* out = (float*)d_out;                 // zs_out (T,H,H) then os (T,H)
    float* ebuf = (float*)d_ws;                 // NC_ * H*H floats = 16 MB

    os_kernel<<<(T_ * H_ + 255) / 256, 256, 0, stream>>>(X, Dv, out + (size_t)T_ * H_ * H_);
    pass1_kernel<<<dim3(NC_, 64), 256, 0, stream>>>(X, Lam, wq, ebuf);
    pass2_kernel<<<64, 256, 0, stream>>>(Lam, ebuf);
    pass3_kernel<<<dim3(NC_, 4), 256, 0, stream>>>(X, Lam, Cm, wq, ebuf, out);
}

// Round 2
// 346.271 us; speedup vs baseline: 1.0435x; 1.0435x over previous
//
#include <hip/hip_runtime.h>

#define L_   8192
#define H_   128
#define T_   4095      // (8192-3)/2 + 1
#define CH_  16        // scan chunk length
#define NC_  256       // number of chunks (255 full + 1 of 15)

typedef __bf16 bf16x8 __attribute__((ext_vector_type(8)));
typedef unsigned short ushort8 __attribute__((ext_vector_type(8)));
typedef float f32x4 __attribute__((ext_vector_type(4)));

__device__ __forceinline__ unsigned short f2bf(float f) {
    // round-to-nearest-even fp32 -> bf16 bits
    unsigned int u = __builtin_bit_cast(unsigned int, f);
    u += 0x7fffu + ((u >> 16) & 1u);
    return (unsigned short)(u >> 16);
}

// ---------------- pass 1: per-chunk local scan end values ----------------
// Same block structure as pass3's scan phase: block = (chunk c, a-tile of 32),
// y[w,d] = wq @ xd shared through LDS (1 block-wide staging instead of 4
// global loads per entry-step).
// ebuf[c][entry] = sum_{s in chunk c} lam^(t_end-s) * u[s]   (zero init)
__global__ __launch_bounds__(256) void pass1_kernel(const float* __restrict__ X,
                                                    const float* __restrict__ Lam,
                                                    const float* __restrict__ wq,
                                                    float* __restrict__ ebuf) {
    __shared__ float y_s[3][128];
    __shared__ float xa_s[3][32];

    const int tid = threadIdx.x;
    const int c   = blockIdx.x;
    const int a0  = blockIdx.y * 32;
    const int a_l = tid & 31;          // owned a-row (local)
    const int dg  = tid >> 5;          // owned d-group (16 d's)

    float z[16], lam[16];
    {
        const float* lp = Lam + (size_t)(a0 + a_l) * H_ + dg * 16;
        #pragma unroll
        for (int j = 0; j < 16; ++j) { lam[j] = lp[j]; z[j] = 0.f; }
    }
    const float w00 = wq[0], w01 = wq[1], w02 = wq[2];
    const float w10 = wq[3], w11 = wq[4], w12 = wq[5];
    const float w20 = wq[6], w21 = wq[7], w22 = wq[8];

    const int t0 = c * CH_;
    const int t1 = min(t0 + CH_, T_);

    for (int t = t0; t < t1; ++t) {
        __syncthreads();
        const float* xr = X + (size_t)(2 * t) * H_;
        if (tid < 128) {
            float xd0 = xr[tid], xd1 = xr[H_ + tid], xd2 = xr[2 * H_ + tid];
            y_s[0][tid] = w00 * xd0 + w01 * xd1 + w02 * xd2;
            y_s[1][tid] = w10 * xd0 + w11 * xd1 + w12 * xd2;
            y_s[2][tid] = w20 * xd0 + w21 * xd1 + w22 * xd2;
        } else if (tid < 224) {
            int li = tid - 128;                       // w = li>>5, a_local = li&31
            xa_s[li >> 5][li & 31] = xr[(li >> 5) * H_ + a0 + (li & 31)];
        }
        __syncthreads();
        const float xa0 = xa_s[0][a_l], xa1 = xa_s[1][a_l], xa2 = xa_s[2][a_l];
        #pragma unroll
        for (int j = 0; j < 16; ++j) {
            const int d = dg * 16 + j;
            float u = xa0 * y_s[0][d] + xa1 * y_s[1][d] + xa2 * y_s[2][d];
            z[j] = fmaf(lam[j], z[j], u);
        }
    }
    float* ep = ebuf + (size_t)c * (H_ * H_) + (size_t)(a0 + a_l) * H_ + dg * 16;
    #pragma unroll
    for (int j = 0; j < 16; ++j) ep[j] = z[j];
}

// ---------------- pass 2: cross-chunk scan, in place e -> carry_in ----------------
__global__ __launch_bounds__(256) void pass2_kernel(const float* __restrict__ Lam,
                                                    float* __restrict__ ebuf) {
    const int entry = blockIdx.x * 256 + threadIdx.x;
    const float lam = Lam[entry];
    float p = lam * lam; p = p * p; p = p * p; p = p * p;   // lam^16
    float z = 0.f;
    for (int cb = 0; cb < NC_; cb += 8) {
        float tmp[8];
        #pragma unroll
        for (int i = 0; i < 8; ++i)
            tmp[i] = ebuf[(size_t)(cb + i) * (H_ * H_) + entry];
        #pragma unroll
        for (int i = 0; i < 8; ++i) {
            ebuf[(size_t)(cb + i) * (H_ * H_) + entry] = z;   // carry_in[chunk]
            z = fmaf(p, z, tmp[i]);
        }
    }
}

// ---------------- pass 3: replay scan from carry + per-t MFMA GEMM ----------------
// block: (chunk c, a-tile of 32).
// MFMA with A = zs (M=a), B = C (N=h): D[a_row, h_col] so each lane's 4 acc
// regs are 4 CONSECUTIVE a values -> one global_store_dwordx4 each.
// out[t, h, a] = sum_d C[h,d] * zs[t, a, d]; also os[t,h] (blockIdx.y==0 only).
__global__ __launch_bounds__(256) void pass3_kernel(const float* __restrict__ X,
                                                    const float* __restrict__ Lam,
                                                    const float* __restrict__ Cm,
                                                    const float* __restrict__ wq,
                                                    const float* __restrict__ Dv,
                                                    const float* __restrict__ carry,
                                                    float* __restrict__ out,
                                                    float* __restrict__ os) {
    __shared__ unsigned short z_s[32][136];   // bf16 zs tile [a_local][d], pad 136 (16B rows)
    __shared__ float y_s[3][128];
    __shared__ float xa_s[3][32];

    const int tid  = threadIdx.x;
    const int c    = blockIdx.x;
    const int a0   = blockIdx.y * 32;
    const int lane = tid & 63;
    const int wave = tid >> 6;
    const int m    = lane & 15;
    const int q    = lane >> 4;

    // B-fragments (N=h): B[k=d][n=h]; lane holds C[(wave*2+ni)*16+m][kt*32+q*8+j].
    // Resident in registers for the whole block.
    ushort8 cfrag[2][4];
    #pragma unroll
    for (int ni = 0; ni < 2; ++ni) {
        const int h = (wave * 2 + ni) * 16 + m;
        #pragma unroll
        for (int kt = 0; kt < 4; ++kt) {
            const float* src = Cm + h * H_ + kt * 32 + q * 8;
            ushort8 v;
            #pragma unroll
            for (int j = 0; j < 8; ++j) v[j] = f2bf(src[j]);
            cfrag[ni][kt] = v;
        }
    }

    // scan ownership: a_l = tid&31 (one a-row), d = dg*16 + j (16 entries)
    const int a_l = tid & 31;
    const int dg  = tid >> 5;
    float z[16], lam[16];
    {
        const float* lp = Lam   + (size_t)(a0 + a_l) * H_ + dg * 16;
        const float* cp = carry + (size_t)c * (H_ * H_) + (size_t)(a0 + a_l) * H_ + dg * 16;
        #pragma unroll
        for (int j = 0; j < 16; ++j) { lam[j] = lp[j]; z[j] = cp[j]; }
    }
    const float w00 = wq[0], w01 = wq[1], w02 = wq[2];
    const float w10 = wq[3], w11 = wq[4], w12 = wq[5];
    const float w20 = wq[6], w21 = wq[7], w22 = wq[8];
    const float d0 = Dv[0], d1 = Dv[1], d2 = Dv[2];
    const bool do_os = (blockIdx.y == 0);

    const int t0 = c * CH_;
    const int t1 = min(t0 + CH_, T_);

    for (int t = t0; t < t1; ++t) {
        __syncthreads();   // z_s free (prev MFMA done), y_s free (prev scan done)
        const float* xr = X + (size_t)(2 * t) * H_;
        if (tid < 128) {
            float xd0 = xr[tid], xd1 = xr[H_ + tid], xd2 = xr[2 * H_ + tid];
            y_s[0][tid] = w00 * xd0 + w01 * xd1 + w02 * xd2;
            y_s[1][tid] = w10 * xd0 + w11 * xd1 + w12 * xd2;
            y_s[2][tid] = w20 * xd0 + w21 * xd1 + w22 * xd2;
            if (do_os) os[t * H_ + tid] = d0 * xd0 + d1 * xd1 + d2 * xd2;
        } else if (tid < 224) {
            int li = tid - 128;                       // w = li>>5, a_local = li&31
            xa_s[li >> 5][li & 31] = xr[(li >> 5) * H_ + a0 + (li & 31)];
        }
        __syncthreads();

        {   // fp32 recurrence in registers; publish bf16 to z_s
            const float xa0 = xa_s[0][a_l], xa1 = xa_s[1][a_l], xa2 = xa_s[2][a_l];
            #pragma unroll
            for (int j = 0; j < 16; ++j) {
                const int d = dg * 16 + j;
                float u = xa0 * y_s[0][d] + xa1 * y_s[1][d] + xa2 * y_s[2][d];
                z[j] = fmaf(lam[j], z[j], u);
            }
            ushort8 zb0, zb1;
            #pragma unroll
            for (int j = 0; j < 8; ++j) { zb0[j] = f2bf(z[j]); zb1[j] = f2bf(z[j + 8]); }
            *(ushort8*)&z_s[a_l][dg * 16]     = zb0;
            *(ushort8*)&z_s[a_l][dg * 16 + 8] = zb1;
        }
        __syncthreads();

        // MFMA: A[m=a_local][k=d] from z_s; B[k=d][n=h] = cfrag.
        f32x4 acc[2][2] = {};   // [mi = a-tile][ni = h-tile]
        #pragma unroll
        for (int kt = 0; kt < 4; ++kt) {
            bf16x8 za = __builtin_bit_cast(bf16x8, *(const ushort8*)&z_s[m][kt * 32 + q * 8]);
            bf16x8 zb = __builtin_bit_cast(bf16x8, *(const ushort8*)&z_s[16 + m][kt * 32 + q * 8]);
            #pragma unroll
            for (int ni = 0; ni < 2; ++ni) {
                bf16x8 cf = __builtin_bit_cast(bf16x8, cfrag[ni][kt]);
                acc[0][ni] = __builtin_amdgcn_mfma_f32_16x16x32_bf16(za, cf, acc[0][ni], 0, 0, 0);
                acc[1][ni] = __builtin_amdgcn_mfma_f32_16x16x32_bf16(zb, cf, acc[1][ni], 0, 0, 0);
            }
        }
        // D layout: row = q*4 + r = a within M-tile, col = m = h within N-tile.
        // acc[mi][ni][0..3] -> out[t, h, a0 + mi*16 + q*4 .. +3]: one dwordx4 store.
        float* ob = out + (size_t)t * (H_ * H_) + a0;
        #pragma unroll
        for (int mi = 0; mi < 2; ++mi) {
            #pragma unroll
            for (int ni = 0; ni < 2; ++ni) {
                const int h = (wave * 2 + ni) * 16 + m;
                *(f32x4*)&ob[(size_t)h * H_ + mi * 16 + q * 4] = acc[mi][ni];
            }
        }
    }
}

extern "C" void kernel_launch(void* const* d_in, const int* in_sizes, int n_in,
                              void* d_out, int out_size, void* d_ws, size_t ws_size,
                              hipStream_t stream) {
    const float* X   = (const float*)d_in[0];   // (L, H)
    const float* Lam = (const float*)d_in[1];   // (H, H)
    const float* Cm  = (const float*)d_in[2];   // (H, H)
    const float* wq  = (const float*)d_in[3];   // (3, 3)
    const float* Dv  = (const float*)d_in[4];   // (3,)
    float* out = (float*)d_out;                 // zs_out (T,H,H) then os (T,H)
    float* os  = out + (size_t)T_ * H_ * H_;
    float* ebuf = (float*)d_ws;                 // NC_ * H*H floats = 16 MB

    pass1_kernel<<<dim3(NC_, 4), 256, 0, stream>>>(X, Lam, wq, ebuf);
    pass2_kernel<<<64, 256, 0, stream>>>(Lam, ebuf);
    pass3_kernel<<<dim3(NC_, 4), 256, 0, stream>>>(X, Lam, Cm, wq, Dv, ebuf, out, os);
}